// Round 12
// baseline (23.101 us; speedup 1.0000x reference)
//
#include <hip/hip_runtime.h>

// Cost volume loss: pred/target (8,3,512,512) f32.
// Per pixel: min over 5x5 offsets (zero-padded target) of mean_C |pred - patch|,
// then global mean. Output: single f32 scalar.
//
// Load-count ladder: r1 78/px=112us, r3/r10 5.25/px=22-23us, r11 3.75/px=19us.
// This round: 3.0 loads/px. Thread = 4 cols x 8 rows (32 px): 12 target rows x
// 3ch x 2 f4-windows = 72 + 24 pred = 96 loads/thread. Block = 128 threads =
// 512 cols x 8 rows (single row-group). Grid = 8 n * 64 hg = 512 blocks.
// Branch-free row loop (clamped row addresses + wave-uniform validity select).
// Border pixels seed best with the zero-pad candidate sum|pred|.

#define H_DIM 512
#define W_DIM 512
#define N_DIM 8
#define C_DIM 3
#define HW (H_DIM * W_DIM)
#define CHW (C_DIM * HW)
#define NPIX (N_DIM * HW)
#define NBLOCKS 512
#define BIGF 3.0e38f

typedef float f4 __attribute__((ext_vector_type(4)));

__global__ __launch_bounds__(128, 1) void cvl_main(const float* __restrict__ pred,
                                                   const float* __restrict__ targ,
                                                   float* __restrict__ partial) {
    const int tid = threadIdx.x;      // 0..127
    const int col = tid;              // 0..127
    const int bid = blockIdx.x;       // 0..511
    const int n   = bid >> 6;         // 0..7
    const int hg  = bid & 63;         // 0..63
    const int h0  = hg * 8;           // first of this thread's 8 rows (block-uniform)
    const int w0  = col * 4;          // first of this thread's 4 cols

    const size_t nbase = (size_t)n * CHW;

    // ---- pred: 8 rows x 3 channels x 4 px, nontemporal (streamed once) ----
    f4 pv[8][3];
#pragma unroll
    for (int r = 0; r < 8; ++r)
#pragma unroll
        for (int c = 0; c < 3; ++c)
            pv[r][c] = __builtin_nontemporal_load(
                (const f4*)(pred + nbase + (size_t)c * HW +
                            (size_t)(h0 + r) * W_DIM + w0));

    const bool wlo = (col == 0);          // w0 == 0
    const bool whi = (col == 127);        // w0 == 508
    const int am = wlo ? 0 : (w0 - 2);            // left window load col
    const int bp = whi ? (W_DIM - 4) : (w0 + 2);  // right window load col
    const float* trow = targ + nbase;

    // ---- seed best: border pixels get the zero-pad candidate sum|pred| ----
    float best[8][4];
#pragma unroll
    for (int r = 0; r < 8; ++r) {
        const int hp = h0 + r;
        const bool hcand = (hp < 2) || (hp >= H_DIM - 2);
#pragma unroll
        for (int px = 0; px < 4; ++px) {
            const bool wcand = (px < 2) ? wlo : whi;
            const float soob =
                fabsf(pv[r][0][px]) + fabsf(pv[r][1][px]) + fabsf(pv[r][2][px]);
            best[r][px] = (hcand || wcand) ? soob : BIGF;
        }
    }

    // ---- 12 target rows, branch-free (clamped addresses) ----
#pragma unroll
    for (int j = 0; j < 12; ++j) {
        const int hh = h0 - 2 + j;                       // block-uniform
        const bool rowok = (hh >= 0) && (hh < H_DIM);    // block-uniform
        const int hc = (hh < 0) ? 0 : ((hh >= H_DIM) ? (H_DIM - 1) : hh);

        // 8-float window per channel: cols [w0-2, w0+6), unconditional loads
        float w[3][8];
#pragma unroll
        for (int c = 0; c < 3; ++c) {
            const float* rowp = trow + (size_t)c * HW + (size_t)hc * W_DIM;
            const f4 a = *(const f4*)(rowp + am);
            const f4 b = *(const f4*)(rowp + bp);
            w[c][0] = a[0];
            w[c][1] = a[1];
            w[c][2] = wlo ? a[0] : a[2];   // col 0 at left edge
            w[c][3] = wlo ? a[1] : a[3];   // col 1 at left edge
            w[c][4] = whi ? b[2] : b[0];   // col 510 at right edge
            w[c][5] = whi ? b[3] : b[1];   // col 511 at right edge
            w[c][6] = b[2];
            w[c][7] = b[3];
        }

#pragma unroll
        for (int r = 0; r < 8; ++r) {
            const int di = j - 2 - r;          // compile-time after unroll
            if (di >= -2 && di <= 2) {
#pragma unroll
                for (int px = 0; px < 4; ++px) {
                    float rm = BIGF;           // min over dj for this row
#pragma unroll
                    for (int dj = -2; dj <= 2; ++dj) {
                        const int ix = px + dj + 2;  // 0..7
                        float s = fabsf(pv[r][0][px] - w[0][ix])
                                + fabsf(pv[r][1][px] - w[1][ix])
                                + fabsf(pv[r][2][px] - w[2][ix]);
                        // out-of-image candidates invalid at w edges:
                        if (px + dj < 0)      s = wlo ? BIGF : s;
                        else if (px + dj > 3) s = whi ? BIGF : s;
                        rm = fminf(rm, s);
                    }
                    // suppress clamped (out-of-image) rows — block-uniform:
                    best[r][px] = fminf(best[r][px], rowok ? rm : BIGF);
                }
            }
        }
    }

    // ---- block reduce: 32 px -> thread, wave shuffle, LDS, one store ----
    float v = 0.0f;
#pragma unroll
    for (int r = 0; r < 8; ++r)
#pragma unroll
        for (int px = 0; px < 4; ++px)
            v += best[r][px];

#pragma unroll
    for (int o = 32; o > 0; o >>= 1) v += __shfl_down(v, o, 64);

    __shared__ float ws[2];
    const int lane = tid & 63;
    const int wv   = tid >> 6;
    if (lane == 0) ws[wv] = v;
    __syncthreads();
    if (tid == 0) partial[bid] = ws[0] + ws[1];
}

__global__ __launch_bounds__(256) void cvl_final(const float* __restrict__ partial,
                                                 float* __restrict__ out) {
    const int tid = threadIdx.x;
    double v = (double)partial[tid] + (double)partial[tid + 256];
#pragma unroll
    for (int o = 32; o > 0; o >>= 1) v += __shfl_down(v, o, 64);

    __shared__ double ws[4];
    const int lane = tid & 63;
    const int wid  = tid >> 6;
    if (lane == 0) ws[wid] = v;
    __syncthreads();
    if (tid == 0) {
        const double s = ws[0] + ws[1] + ws[2] + ws[3];
        out[0] = (float)(s / (3.0 * (double)NPIX));
    }
}

extern "C" void kernel_launch(void* const* d_in, const int* in_sizes, int n_in,
                              void* d_out, int out_size, void* d_ws, size_t ws_size,
                              hipStream_t stream) {
    const float* pred = (const float*)d_in[0];
    const float* targ = (const float*)d_in[1];
    float* out = (float*)d_out;
    float* partial = (float*)d_ws;

    cvl_main<<<NBLOCKS, 128, 0, stream>>>(pred, targ, partial);
    cvl_final<<<1, 256, 0, stream>>>(partial, out);
}